// Round 13
// baseline (238.749 us; speedup 1.0000x reference)
//
#include <hip/hip_runtime.h>
#include <hip/hip_bf16.h>

#define NSTEP 50
#define S51 51
#define HID 128
#define MT 64                  // rows per tile
#define BPB 16                 // batch elems per block (block owns them -> no global atomics)
#define RPB (BPB * S51)        // 816 valid rows per block
#define NTILE 13               // ceil(816/64): 832 rows, 16 masked (1.9% waste)
#define GRID (16384 / BPB)     // 1024 blocks
#define BLOCK 256              // 4 waves; wave mi owns hidden slice [mi*32, mi*32+32)

typedef __attribute__((ext_vector_type(2))) float floatx2;
typedef __attribute__((ext_vector_type(4))) float floatx4;
typedef __attribute__((ext_vector_type(16))) float floatx16;

// 4 x f32 -> 4 packed fp8 e4m3 bytes (v_cvt_pk_fp8_f32, gfx950 OCP e4m3fn)
__device__ __forceinline__ unsigned pk4_fp8(float v0, float v1, float v2, float v3) {
    unsigned r = (unsigned)__builtin_amdgcn_cvt_pk_fp8_f32(v0, v1, 0, false);   // bytes 0,1
    r = (unsigned)__builtin_amdgcn_cvt_pk_fp8_f32(v2, v3, (int)r, true);        // bytes 2,3
    return r;
}

// Swizzled fp8 activation layout: row-major 64x128 bytes, rows = 16 chunks of 8B,
// phys_chunk = chunk ^ (row & 15). 8B-aligned for ds_read/write_b64.
__device__ __forceinline__ int sw8(int row, int chunk) {
    return row * HID + ((chunk ^ (row & 15)) << 3);   // in bytes
}

// Register-only C-operand build (address-taken aggregates spill — R7 lesson)
__device__ __forceinline__ floatx16 ld_bias16(const float* bs, int base) {
    const floatx4 t0 = *(const floatx4*)(&bs[base]);
    const floatx4 t1 = *(const floatx4*)(&bs[base + 8]);
    const floatx4 t2 = *(const floatx4*)(&bs[base + 16]);
    const floatx4 t3 = *(const floatx4*)(&bs[base + 24]);
    floatx16 v = {t0[0], t0[1], t0[2], t0[3], t1[0], t1[1], t1[2], t1[3],
                  t2[0], t2[1], t2[2], t2[3], t3[0], t3[1], t3[2], t3[3]};
    return v;
}

// Packed-f32 L1: 8 k-outputs as 4x float2 pk_fma chains -> 8 fp8 bytes.
// v_pk_fma_f32 / v_pk_max_f32 are full-rate 2xf32 on CDNA.
__device__ __forceinline__ unsigned long long l1_chunk8(const float* w1s, const float* b1s,
                                                        int kc0, floatx2 X2, floatx2 h2) {
    const floatx2 z2 = {0.0f, 0.0f};
    unsigned b[2];
#pragma unroll
    for (int p = 0; p < 2; ++p) {
        const int k = kc0 + 4 * p;
        floatx2 u0 = __builtin_elementwise_fma(X2, *(const floatx2*)(&w1s[k]),
                     __builtin_elementwise_fma(h2, *(const floatx2*)(&w1s[HID + k]),
                                               *(const floatx2*)(&b1s[k])));
        floatx2 u1 = __builtin_elementwise_fma(X2, *(const floatx2*)(&w1s[k + 2]),
                     __builtin_elementwise_fma(h2, *(const floatx2*)(&w1s[HID + k + 2]),
                                               *(const floatx2*)(&b1s[k + 2])));
        u0 = __builtin_elementwise_max(u0, z2);
        u1 = __builtin_elementwise_max(u1, z2);
        b[p] = pk4_fp8(u0[0], u0[1], u1[0], u1[1]);
    }
    return ((unsigned long long)b[1] << 32) | (unsigned long long)b[0];
}

// R12 double-pumped pipeline (one barrier/tile, L2(s) + L3(s-1) concurrent,
// parity double-buffered LDS) with the three scalar-f32 hot spots rewritten as
// packed 2xf32 (pk_fma/pk_max): L1, epilogue relu, fused-L4 dot.
__launch_bounds__(BLOCK, 4)
__global__ void monotonic_fused(const float* __restrict__ x, const float* __restrict__ h,
                                const float* __restrict__ w1, const float* __restrict__ b1,
                                const float* __restrict__ w2, const float* __restrict__ b2,
                                const float* __restrict__ w3, const float* __restrict__ b3,
                                const float* __restrict__ w4, const float* __restrict__ b4,
                                float* __restrict__ out) {
    __shared__ __align__(16) unsigned char A1[2][MT * HID];  // a1 fp8, 2 x 8 KB
    __shared__ __align__(16) unsigned char A2[2][MT * HID];  // a2 fp8, 2 x 8 KB
    __shared__ float w1s[2 * HID], b1s[HID], b2s[HID], b3s[HID], w4s[HID];
    __shared__ float fs[S51], ts[S51];
    __shared__ float xs[BPB], hs[BPB], osum[BPB];
    __shared__ float posum[2][4][MT];                        // parity x mi x row
    __shared__ unsigned short rowmap[NTILE * MT];            // (bbl<<6)|ss per row

    const int tid = threadIdx.x;
    const int lane = tid & 63;
    const int mi = tid >> 6;      // wave 0..3 = hidden 32-slice
    const int l31 = lane & 31;
    const int hi = lane >> 5;
    const int r1 = tid >> 2;          // L1 writer: row 0..63
    const int cb = (tid & 3) * 4;     // L1 writer: base chunk (4 chunks = 32 k-cols)

    // ---- stage small tensors ----
    w1s[tid] = w1[tid];               // 256 threads = 256 elems exactly
    if (tid < HID) {
        b1s[tid] = b1[tid]; b2s[tid] = b2[tid]; b3s[tid] = b3[tid]; w4s[tid] = w4[tid];
    }
    if (tid < BPB) {
        xs[tid] = x[blockIdx.x * BPB + tid];
        hs[tid] = h[blockIdx.x * BPB + tid];
        osum[tid] = 0.0f;
    }
    for (int i = tid; i < NTILE * MT; i += BLOCK) {
        int lrc = i < RPB ? i : RPB - 1;
        unsigned bbl = (unsigned)lrc / 51u;
        int ss = lrc - (int)bbl * 51;
        rowmap[i] = (unsigned short)((bbl << 6) | ss);
    }
    if (tid < S51) {
        // Faithful port of compute_cc_weights (verified R1-R12)
        const float PI50 = 0.06283185307179586f;  // pi/50
        float acc = 1.0f;
        for (int i = 2; i <= 50; i += 2) {
            int m = (i * tid) % 100;  // exact argument reduction
            acc += (2.0f / (1.0f - (float)(i * i))) * cosf((float)m * PI50);
        }
        float ccw = acc * 0.04f * ((tid == 0 || tid == NSTEP) ? 0.5f : 1.0f);
        fs[tid] = ccw * 0.5f;                               // folds the (x-x0)*0.5 factor
        ts[tid] = (cosf((float)tid * PI50) + 1.0f) * 0.5f;  // (steps+1)/2
    }
    const float b4v = b4[0];

    // ---- gather W2^T / W3^T A-operand fp8 fragments (coalesced over l31) ----
    // frag[kc] byte e = W[kc*16 + hi*8 + e][mi*32 + l31]
    long w2f[8], w3f[8];
    {
        const int irow = mi * 32 + l31;
#pragma unroll
        for (int kc = 0; kc < 8; ++kc) {
            const int kb = kc * 16 + hi * 8;
            unsigned lo2 = pk4_fp8(w2[(kb + 0) * HID + irow], w2[(kb + 1) * HID + irow],
                                   w2[(kb + 2) * HID + irow], w2[(kb + 3) * HID + irow]);
            unsigned hi2 = pk4_fp8(w2[(kb + 4) * HID + irow], w2[(kb + 5) * HID + irow],
                                   w2[(kb + 6) * HID + irow], w2[(kb + 7) * HID + irow]);
            w2f[kc] = (long)(((unsigned long long)hi2 << 32) | lo2);
            unsigned lo3 = pk4_fp8(w3[(kb + 0) * HID + irow], w3[(kb + 1) * HID + irow],
                                   w3[(kb + 2) * HID + irow], w3[(kb + 3) * HID + irow]);
            unsigned hi3 = pk4_fp8(w3[(kb + 4) * HID + irow], w3[(kb + 5) * HID + irow],
                                   w3[(kb + 6) * HID + irow], w3[(kb + 7) * HID + irow]);
            w3f[kc] = (long)(((unsigned long long)hi3 << 32) | lo3);
        }
    }
    __syncthreads();

    // ---- L1 for tile 0 -> A1[0] (packed) ----
    {
        unsigned mm = rowmap[r1];
        unsigned bbl = mm >> 6;
        int ss = mm & 63;
        float X = xs[bbl] * ts[ss], hb = hs[bbl];
        const floatx2 X2 = {X, X}, h2 = {hb, hb};
#pragma unroll
        for (int cc = 0; cc < 4; ++cc)
            *(unsigned long long*)(&A1[0][sw8(r1, cb + cc)]) =
                l1_chunk8(w1s, b1s, (cb + cc) * 8, X2, h2);
    }
    __syncthreads();

    const floatx16 z16 = {0.f,0.f,0.f,0.f,0.f,0.f,0.f,0.f,0.f,0.f,0.f,0.f,0.f,0.f,0.f,0.f};

    for (int s = 0; s <= NTILE; ++s) {
        const int pa = s & 1, pb = pa ^ 1;
        floatx16 a0, a1, c0, c1;

        // ---- L2-MFMA on tile s (read A1[pa]); bias as C of peeled MFMA ----
        if (s < NTILE) {
            const floatx16 ci = ld_bias16(b2s, mi * 32 + 4 * hi);
            long f0 = *(const long*)(&A1[pa][sw8(l31, hi)]);
            long f1 = *(const long*)(&A1[pa][sw8(l31 + 32, hi)]);
            a0 = __builtin_amdgcn_mfma_f32_32x32x16_fp8_fp8(w2f[0], f0, ci, 0, 0, 0);
            a1 = __builtin_amdgcn_mfma_f32_32x32x16_fp8_fp8(w2f[0], f1, ci, 0, 0, 0);
#pragma unroll
            for (int kc = 1; kc < 8; ++kc) {
                f0 = *(const long*)(&A1[pa][sw8(l31, kc * 2 + hi)]);
                f1 = *(const long*)(&A1[pa][sw8(l31 + 32, kc * 2 + hi)]);
                a0 = __builtin_amdgcn_mfma_f32_32x32x16_fp8_fp8(w2f[kc], f0, a0, 0, 0, 0);
                a1 = __builtin_amdgcn_mfma_f32_32x32x16_fp8_fp8(w2f[kc], f1, a1, 0, 0, 0);
            }
        }
        // ---- L3-MFMA on tile s-1 (read A2[pb]) — independent chain, overlaps L2 ----
        if (s >= 1) {
            const floatx16 ci = ld_bias16(b3s, mi * 32 + 4 * hi);
            long g0 = *(const long*)(&A2[pb][sw8(l31, hi)]);
            long g1 = *(const long*)(&A2[pb][sw8(l31 + 32, hi)]);
            c0 = __builtin_amdgcn_mfma_f32_32x32x16_fp8_fp8(w3f[0], g0, ci, 0, 0, 0);
            c1 = __builtin_amdgcn_mfma_f32_32x32x16_fp8_fp8(w3f[0], g1, ci, 0, 0, 0);
#pragma unroll
            for (int kc = 1; kc < 8; ++kc) {
                g0 = *(const long*)(&A2[pb][sw8(l31, kc * 2 + hi)]);
                g1 = *(const long*)(&A2[pb][sw8(l31 + 32, kc * 2 + hi)]);
                c0 = __builtin_amdgcn_mfma_f32_32x32x16_fp8_fp8(w3f[kc], g0, c0, 0, 0, 0);
                c1 = __builtin_amdgcn_mfma_f32_32x32x16_fp8_fp8(w3f[kc], g1, c1, 0, 0, 0);
            }
        }
        // ---- consume tile s-2 partials (posum[pa]; written phase s-1, barrier apart) ----
        if (s >= 2 && tid < MT) {
            int lr = (s - 2) * MT + tid;
            float u = posum[pa][0][tid] + posum[pa][1][tid] + posum[pa][2][tid]
                    + posum[pa][3][tid] + b4v;
            if (lr < RPB) {
                unsigned mm = rowmap[lr];
                float dz = u > 0.0f ? u + 1.0f : __expf(u);  // elu(u)+1
                atomicAdd(&osum[mm >> 6], dz * fs[mm & 63]);
            }
        }
        // ---- epilogue: relu(a) -> A2[pa] fp8 (packed max) ----
        if (s < NTILE) {
            const floatx16 am0 = __builtin_elementwise_max(a0, z16);
            const floatx16 am1 = __builtin_elementwise_max(a1, z16);
#pragma unroll
            for (int g = 0; g < 4; ++g) {
                const int chI = mi * 4 + g;
                *(unsigned*)(&A2[pa][sw8(l31, chI) + 4 * hi]) =
                    pk4_fp8(am0[4 * g + 0], am0[4 * g + 1], am0[4 * g + 2], am0[4 * g + 3]);
                *(unsigned*)(&A2[pa][sw8(l31 + 32, chI) + 4 * hi]) =
                    pk4_fp8(am1[4 * g + 0], am1[4 * g + 1], am1[4 * g + 2], am1[4 * g + 3]);
            }
        }
        // ---- fused L4 for tile s-1 -> posum[pb] (packed dot, plain stores) ----
        if (s >= 1) {
            const floatx16 m0 = __builtin_elementwise_max(c0, z16);
            const floatx16 m1 = __builtin_elementwise_max(c1, z16);
            floatx2 q0 = {0.0f, 0.0f}, q1 = {0.0f, 0.0f};
#pragma unroll
            for (int g = 0; g < 4; ++g) {
#pragma unroll
                for (int p = 0; p < 2; ++p) {
                    const floatx2 w4p = *(const floatx2*)(&w4s[mi * 32 + 8 * g + 4 * hi + 2 * p]);
                    const floatx2 c0p = {m0[4 * g + 2 * p], m0[4 * g + 2 * p + 1]};
                    const floatx2 c1p = {m1[4 * g + 2 * p], m1[4 * g + 2 * p + 1]};
                    q0 = __builtin_elementwise_fma(c0p, w4p, q0);
                    q1 = __builtin_elementwise_fma(c1p, w4p, q1);
                }
            }
            float p0 = q0[0] + q0[1], p1 = q1[0] + q1[1];
            p0 += __shfl_xor(p0, 32);
            p1 += __shfl_xor(p1, 32);
            if (hi == 0) {
                posum[pb][mi][l31] = p0;
                posum[pb][mi][l31 + 32] = p1;
            }
        }
        // ---- L1 for tile s+1 -> A1[pb] (packed; A1[pb] last read in phase s-1) ----
        if (s + 1 < NTILE) {
            int lr = (s + 1) * MT + r1;
            unsigned mm = rowmap[lr];
            unsigned bbl = mm >> 6;
            int ss = mm & 63;
            float X = xs[bbl] * ts[ss], hb = hs[bbl];
            const floatx2 X2 = {X, X}, h2 = {hb, hb};
#pragma unroll
            for (int cc = 0; cc < 4; ++cc)
                *(unsigned long long*)(&A1[pb][sw8(r1, cb + cc)]) =
                    l1_chunk8(w1s, b1s, (cb + cc) * 8, X2, h2);
        }
        __syncthreads();
    }

    // final consume: tile NTILE-1 partials (written in phase s=NTILE to posum[(NTILE-1)&1])
    if (tid < MT) {
        int lr = (NTILE - 1) * MT + tid;
        if (lr < RPB) {
            const int pf = (NTILE - 1) & 1;
            float u = posum[pf][0][tid] + posum[pf][1][tid] + posum[pf][2][tid]
                    + posum[pf][3][tid] + b4v;
            unsigned mm = rowmap[lr];
            float dz = u > 0.0f ? u + 1.0f : __expf(u);
            atomicAdd(&osum[mm >> 6], dz * fs[mm & 63]);
        }
    }
    __syncthreads();

    if (tid < BPB) out[blockIdx.x * BPB + tid] = hs[tid] + osum[tid] * xs[tid];
}

extern "C" void kernel_launch(void* const* d_in, const int* in_sizes, int n_in,
                              void* d_out, int out_size, void* d_ws, size_t ws_size,
                              hipStream_t stream) {
    const float* x  = (const float*)d_in[0];
    const float* h  = (const float*)d_in[1];
    const float* w1 = (const float*)d_in[2];
    const float* b1 = (const float*)d_in[3];
    const float* w2 = (const float*)d_in[4];
    const float* b2 = (const float*)d_in[5];
    const float* w3 = (const float*)d_in[6];
    const float* b3 = (const float*)d_in[7];
    const float* w4 = (const float*)d_in[8];
    const float* b4 = (const float*)d_in[9];
    float* out = (float*)d_out;

    monotonic_fused<<<GRID, BLOCK, 0, stream>>>(x, h, w1, b1, w2, b2, w3, b3, w4, b4, out);
}

// Round 14
// 152.340 us; speedup vs baseline: 1.5672x; 1.5672x over previous
//
#include <hip/hip_runtime.h>
#include <hip/hip_bf16.h>

#define NSTEP 50
#define S51 51
#define HID 128
#define MT 64                  // rows per tile
#define BPB 16                 // batch elems per block (block owns them -> no global atomics)
#define RPB (BPB * S51)        // 816 valid rows per block
#define NTILE 13               // ceil(816/64): 832 rows, 16 masked (1.9% waste)
#define GRID (16384 / BPB)     // 1024 blocks
#define BLOCK 256              // 4 waves; wave mi owns hidden slice [mi*32, mi*32+32)

typedef __attribute__((ext_vector_type(2))) float floatx2;
typedef __attribute__((ext_vector_type(4))) float floatx4;
typedef __attribute__((ext_vector_type(16))) float floatx16;

// 4 x f32 -> 4 packed fp8 e4m3 bytes (v_cvt_pk_fp8_f32, gfx950 OCP e4m3fn)
__device__ __forceinline__ unsigned pk4_fp8(float v0, float v1, float v2, float v3) {
    unsigned r = (unsigned)__builtin_amdgcn_cvt_pk_fp8_f32(v0, v1, 0, false);   // bytes 0,1
    r = (unsigned)__builtin_amdgcn_cvt_pk_fp8_f32(v2, v3, (int)r, true);        // bytes 2,3
    return r;
}

// Swizzled fp8 activation layout: row-major 64x128 bytes, rows = 16 chunks of 8B,
// phys_chunk = chunk ^ (row & 15). 8B-aligned for ds_read/write_b64.
__device__ __forceinline__ int sw8(int row, int chunk) {
    return row * HID + ((chunk ^ (row & 15)) << 3);   // in bytes
}

// Register-only C-operand build (address-taken aggregates spill — R7 lesson)
__device__ __forceinline__ floatx16 ld_bias16(const float* bs, int base) {
    const floatx4 t0 = *(const floatx4*)(&bs[base]);
    const floatx4 t1 = *(const floatx4*)(&bs[base + 8]);
    const floatx4 t2 = *(const floatx4*)(&bs[base + 16]);
    const floatx4 t3 = *(const floatx4*)(&bs[base + 24]);
    floatx16 v = {t0[0], t0[1], t0[2], t0[3], t1[0], t1[1], t1[2], t1[3],
                  t2[0], t2[1], t2[2], t2[3], t3[0], t3[1], t3[2], t3[3]};
    return v;
}

// Packed-f32 L1 (loop-scoped floatx2 temps only — register-safe, R13-verified part).
__device__ __forceinline__ unsigned long long l1_chunk8(const float* w1s, const float* b1s,
                                                        int kc0, floatx2 X2, floatx2 h2) {
    const floatx2 z2 = {0.0f, 0.0f};
    unsigned b[2];
#pragma unroll
    for (int p = 0; p < 2; ++p) {
        const int k = kc0 + 4 * p;
        floatx2 u0 = __builtin_elementwise_fma(X2, *(const floatx2*)(&w1s[k]),
                     __builtin_elementwise_fma(h2, *(const floatx2*)(&w1s[HID + k]),
                                               *(const floatx2*)(&b1s[k])));
        floatx2 u1 = __builtin_elementwise_fma(X2, *(const floatx2*)(&w1s[k + 2]),
                     __builtin_elementwise_fma(h2, *(const floatx2*)(&w1s[HID + k + 2]),
                                               *(const floatx2*)(&b1s[k + 2])));
        u0 = __builtin_elementwise_max(u0, z2);
        u1 = __builtin_elementwise_max(u1, z2);
        b[p] = pk4_fp8(u0[0], u0[1], u1[0], u1[1]);
    }
    return ((unsigned long long)b[1] << 32) | (unsigned long long)b[0];
}

// R12 double-pumped pipeline (one barrier/tile, L2(s)+L3(s-1) concurrent, parity
// double-buffered LDS) + packed f32 in L1/epilogue/L4 with STRICTLY loop-scoped
// temps. R13's whole-vector max temps (4 x floatx16 = 64 regs) caused remat
// (FETCH 300 MB); here peak live registers match R12 exactly.
__launch_bounds__(BLOCK, 4)
__global__ void monotonic_fused(const float* __restrict__ x, const float* __restrict__ h,
                                const float* __restrict__ w1, const float* __restrict__ b1,
                                const float* __restrict__ w2, const float* __restrict__ b2,
                                const float* __restrict__ w3, const float* __restrict__ b3,
                                const float* __restrict__ w4, const float* __restrict__ b4,
                                float* __restrict__ out) {
    __shared__ __align__(16) unsigned char A1[2][MT * HID];  // a1 fp8, 2 x 8 KB
    __shared__ __align__(16) unsigned char A2[2][MT * HID];  // a2 fp8, 2 x 8 KB
    __shared__ float w1s[2 * HID], b1s[HID], b2s[HID], b3s[HID], w4s[HID];
    __shared__ float fs[S51], ts[S51];
    __shared__ float xs[BPB], hs[BPB], osum[BPB];
    __shared__ float posum[2][4][MT];                        // parity x mi x row
    __shared__ unsigned short rowmap[NTILE * MT];            // (bbl<<6)|ss per row

    const int tid = threadIdx.x;
    const int lane = tid & 63;
    const int mi = tid >> 6;      // wave 0..3 = hidden 32-slice
    const int l31 = lane & 31;
    const int hi = lane >> 5;
    const int r1 = tid >> 2;          // L1 writer: row 0..63
    const int cb = (tid & 3) * 4;     // L1 writer: base chunk (4 chunks = 32 k-cols)

    // ---- stage small tensors ----
    w1s[tid] = w1[tid];               // 256 threads = 256 elems exactly
    if (tid < HID) {
        b1s[tid] = b1[tid]; b2s[tid] = b2[tid]; b3s[tid] = b3[tid]; w4s[tid] = w4[tid];
    }
    if (tid < BPB) {
        xs[tid] = x[blockIdx.x * BPB + tid];
        hs[tid] = h[blockIdx.x * BPB + tid];
        osum[tid] = 0.0f;
    }
    for (int i = tid; i < NTILE * MT; i += BLOCK) {
        int lrc = i < RPB ? i : RPB - 1;
        unsigned bbl = (unsigned)lrc / 51u;
        int ss = lrc - (int)bbl * 51;
        rowmap[i] = (unsigned short)((bbl << 6) | ss);
    }
    if (tid < S51) {
        // Faithful port of compute_cc_weights (verified R1-R13)
        const float PI50 = 0.06283185307179586f;  // pi/50
        float acc = 1.0f;
        for (int i = 2; i <= 50; i += 2) {
            int m = (i * tid) % 100;  // exact argument reduction
            acc += (2.0f / (1.0f - (float)(i * i))) * cosf((float)m * PI50);
        }
        float ccw = acc * 0.04f * ((tid == 0 || tid == NSTEP) ? 0.5f : 1.0f);
        fs[tid] = ccw * 0.5f;                               // folds the (x-x0)*0.5 factor
        ts[tid] = (cosf((float)tid * PI50) + 1.0f) * 0.5f;  // (steps+1)/2
    }
    const float b4v = b4[0];

    // ---- gather W2^T / W3^T A-operand fp8 fragments (coalesced over l31) ----
    // frag[kc] byte e = W[kc*16 + hi*8 + e][mi*32 + l31]
    long w2f[8], w3f[8];
    {
        const int irow = mi * 32 + l31;
#pragma unroll
        for (int kc = 0; kc < 8; ++kc) {
            const int kb = kc * 16 + hi * 8;
            unsigned lo2 = pk4_fp8(w2[(kb + 0) * HID + irow], w2[(kb + 1) * HID + irow],
                                   w2[(kb + 2) * HID + irow], w2[(kb + 3) * HID + irow]);
            unsigned hi2 = pk4_fp8(w2[(kb + 4) * HID + irow], w2[(kb + 5) * HID + irow],
                                   w2[(kb + 6) * HID + irow], w2[(kb + 7) * HID + irow]);
            w2f[kc] = (long)(((unsigned long long)hi2 << 32) | lo2);
            unsigned lo3 = pk4_fp8(w3[(kb + 0) * HID + irow], w3[(kb + 1) * HID + irow],
                                   w3[(kb + 2) * HID + irow], w3[(kb + 3) * HID + irow]);
            unsigned hi3 = pk4_fp8(w3[(kb + 4) * HID + irow], w3[(kb + 5) * HID + irow],
                                   w3[(kb + 6) * HID + irow], w3[(kb + 7) * HID + irow]);
            w3f[kc] = (long)(((unsigned long long)hi3 << 32) | lo3);
        }
    }
    __syncthreads();

    // ---- L1 for tile 0 -> A1[0] (packed, scoped) ----
    {
        unsigned mm = rowmap[r1];
        unsigned bbl = mm >> 6;
        int ss = mm & 63;
        float X = xs[bbl] * ts[ss], hb = hs[bbl];
        const floatx2 X2 = {X, X}, h2 = {hb, hb};
#pragma unroll
        for (int cc = 0; cc < 4; ++cc)
            *(unsigned long long*)(&A1[0][sw8(r1, cb + cc)]) =
                l1_chunk8(w1s, b1s, (cb + cc) * 8, X2, h2);
    }
    __syncthreads();

    for (int s = 0; s <= NTILE; ++s) {
        const int pa = s & 1, pb = pa ^ 1;
        floatx16 a0, a1, c0, c1;

        // ---- L2-MFMA on tile s (read A1[pa]); bias as C of peeled MFMA ----
        if (s < NTILE) {
            const floatx16 ci = ld_bias16(b2s, mi * 32 + 4 * hi);
            long f0 = *(const long*)(&A1[pa][sw8(l31, hi)]);
            long f1 = *(const long*)(&A1[pa][sw8(l31 + 32, hi)]);
            a0 = __builtin_amdgcn_mfma_f32_32x32x16_fp8_fp8(w2f[0], f0, ci, 0, 0, 0);
            a1 = __builtin_amdgcn_mfma_f32_32x32x16_fp8_fp8(w2f[0], f1, ci, 0, 0, 0);
#pragma unroll
            for (int kc = 1; kc < 8; ++kc) {
                f0 = *(const long*)(&A1[pa][sw8(l31, kc * 2 + hi)]);
                f1 = *(const long*)(&A1[pa][sw8(l31 + 32, kc * 2 + hi)]);
                a0 = __builtin_amdgcn_mfma_f32_32x32x16_fp8_fp8(w2f[kc], f0, a0, 0, 0, 0);
                a1 = __builtin_amdgcn_mfma_f32_32x32x16_fp8_fp8(w2f[kc], f1, a1, 0, 0, 0);
            }
        }
        // ---- L3-MFMA on tile s-1 (read A2[pb]) — independent chain, overlaps L2 ----
        if (s >= 1) {
            const floatx16 ci = ld_bias16(b3s, mi * 32 + 4 * hi);
            long g0 = *(const long*)(&A2[pb][sw8(l31, hi)]);
            long g1 = *(const long*)(&A2[pb][sw8(l31 + 32, hi)]);
            c0 = __builtin_amdgcn_mfma_f32_32x32x16_fp8_fp8(w3f[0], g0, ci, 0, 0, 0);
            c1 = __builtin_amdgcn_mfma_f32_32x32x16_fp8_fp8(w3f[0], g1, ci, 0, 0, 0);
#pragma unroll
            for (int kc = 1; kc < 8; ++kc) {
                g0 = *(const long*)(&A2[pb][sw8(l31, kc * 2 + hi)]);
                g1 = *(const long*)(&A2[pb][sw8(l31 + 32, kc * 2 + hi)]);
                c0 = __builtin_amdgcn_mfma_f32_32x32x16_fp8_fp8(w3f[kc], g0, c0, 0, 0, 0);
                c1 = __builtin_amdgcn_mfma_f32_32x32x16_fp8_fp8(w3f[kc], g1, c1, 0, 0, 0);
            }
        }
        // ---- consume tile s-2 partials (posum[pa]; written phase s-1, barrier apart) ----
        if (s >= 2 && tid < MT) {
            int lr = (s - 2) * MT + tid;
            float u = posum[pa][0][tid] + posum[pa][1][tid] + posum[pa][2][tid]
                    + posum[pa][3][tid] + b4v;
            if (lr < RPB) {
                unsigned mm = rowmap[lr];
                float dz = u > 0.0f ? u + 1.0f : __expf(u);  // elu(u)+1
                atomicAdd(&osum[mm >> 6], dz * fs[mm & 63]);
            }
        }
        // ---- epilogue: relu(a) -> A2[pa] fp8 (packed max, scoped temps) ----
        if (s < NTILE) {
            const floatx2 z2 = {0.0f, 0.0f};
#pragma unroll
            for (int g = 0; g < 4; ++g) {
                const int chI = mi * 4 + g;
                floatx2 e0 = __builtin_elementwise_max((floatx2){a0[4 * g + 0], a0[4 * g + 1]}, z2);
                floatx2 e1 = __builtin_elementwise_max((floatx2){a0[4 * g + 2], a0[4 * g + 3]}, z2);
                *(unsigned*)(&A2[pa][sw8(l31, chI) + 4 * hi]) =
                    pk4_fp8(e0[0], e0[1], e1[0], e1[1]);
                e0 = __builtin_elementwise_max((floatx2){a1[4 * g + 0], a1[4 * g + 1]}, z2);
                e1 = __builtin_elementwise_max((floatx2){a1[4 * g + 2], a1[4 * g + 3]}, z2);
                *(unsigned*)(&A2[pa][sw8(l31 + 32, chI) + 4 * hi]) =
                    pk4_fp8(e0[0], e0[1], e1[0], e1[1]);
            }
        }
        // ---- fused L4 for tile s-1 -> posum[pb] (packed dot, scoped temps) ----
        if (s >= 1) {
            const floatx2 z2 = {0.0f, 0.0f};
            floatx2 q0 = {0.0f, 0.0f}, q1 = {0.0f, 0.0f};
#pragma unroll
            for (int g = 0; g < 4; ++g) {
#pragma unroll
                for (int p = 0; p < 2; ++p) {
                    const floatx2 w4p = *(const floatx2*)(&w4s[mi * 32 + 8 * g + 4 * hi + 2 * p]);
                    floatx2 c0p = __builtin_elementwise_max(
                        (floatx2){c0[4 * g + 2 * p], c0[4 * g + 2 * p + 1]}, z2);
                    floatx2 c1p = __builtin_elementwise_max(
                        (floatx2){c1[4 * g + 2 * p], c1[4 * g + 2 * p + 1]}, z2);
                    q0 = __builtin_elementwise_fma(c0p, w4p, q0);
                    q1 = __builtin_elementwise_fma(c1p, w4p, q1);
                }
            }
            float p0 = q0[0] + q0[1], p1 = q1[0] + q1[1];
            p0 += __shfl_xor(p0, 32);
            p1 += __shfl_xor(p1, 32);
            if (hi == 0) {
                posum[pb][mi][l31] = p0;
                posum[pb][mi][l31 + 32] = p1;
            }
        }
        // ---- L1 for tile s+1 -> A1[pb] (packed; A1[pb] last read in phase s-1) ----
        if (s + 1 < NTILE) {
            int lr = (s + 1) * MT + r1;
            unsigned mm = rowmap[lr];
            unsigned bbl = mm >> 6;
            int ss = mm & 63;
            float X = xs[bbl] * ts[ss], hb = hs[bbl];
            const floatx2 X2 = {X, X}, h2 = {hb, hb};
#pragma unroll
            for (int cc = 0; cc < 4; ++cc)
                *(unsigned long long*)(&A1[pb][sw8(r1, cb + cc)]) =
                    l1_chunk8(w1s, b1s, (cb + cc) * 8, X2, h2);
        }
        __syncthreads();
    }

    // final consume: tile NTILE-1 partials (written in phase s=NTILE to posum[(NTILE-1)&1])
    if (tid < MT) {
        int lr = (NTILE - 1) * MT + tid;
        if (lr < RPB) {
            const int pf = (NTILE - 1) & 1;
            float u = posum[pf][0][tid] + posum[pf][1][tid] + posum[pf][2][tid]
                    + posum[pf][3][tid] + b4v;
            unsigned mm = rowmap[lr];
            float dz = u > 0.0f ? u + 1.0f : __expf(u);
            atomicAdd(&osum[mm >> 6], dz * fs[mm & 63]);
        }
    }
    __syncthreads();

    if (tid < BPB) out[blockIdx.x * BPB + tid] = hs[tid] + osum[tid] * xs[tid];
}

extern "C" void kernel_launch(void* const* d_in, const int* in_sizes, int n_in,
                              void* d_out, int out_size, void* d_ws, size_t ws_size,
                              hipStream_t stream) {
    const float* x  = (const float*)d_in[0];
    const float* h  = (const float*)d_in[1];
    const float* w1 = (const float*)d_in[2];
    const float* b1 = (const float*)d_in[3];
    const float* w2 = (const float*)d_in[4];
    const float* b2 = (const float*)d_in[5];
    const float* w3 = (const float*)d_in[6];
    const float* b3 = (const float*)d_in[7];
    const float* w4 = (const float*)d_in[8];
    const float* b4 = (const float*)d_in[9];
    float* out = (float*)d_out;

    monotonic_fused<<<GRID, BLOCK, 0, stream>>>(x, h, w1, b1, w2, b2, w3, b3, w4, b4, out);
}

// Round 15
// 147.462 us; speedup vs baseline: 1.6191x; 1.0331x over previous
//
#include <hip/hip_runtime.h>
#include <hip/hip_bf16.h>

#define NSTEP 50
#define S51 51
#define HID 128
#define MT 64                  // rows per tile
#define BPB 16                 // batch elems per block (block owns them -> no global atomics)
#define RPB (BPB * S51)        // 816 valid rows per block
#define NTILE 13               // ceil(816/64): 832 rows, 16 masked (1.9% waste)
#define GRID (16384 / BPB)     // 1024 blocks
#define BLOCK 256              // 4 waves; wave mi owns hidden slice [mi*32, mi*32+32)

typedef __attribute__((ext_vector_type(4))) float floatx4;
typedef __attribute__((ext_vector_type(16))) float floatx16;

// 4 x f32 -> 4 packed fp8 e4m3 bytes (v_cvt_pk_fp8_f32, gfx950 OCP e4m3fn)
__device__ __forceinline__ unsigned pk4_fp8(float v0, float v1, float v2, float v3) {
    unsigned r = (unsigned)__builtin_amdgcn_cvt_pk_fp8_f32(v0, v1, 0, false);   // bytes 0,1
    r = (unsigned)__builtin_amdgcn_cvt_pk_fp8_f32(v2, v3, (int)r, true);        // bytes 2,3
    return r;
}

// Swizzled fp8 activation layout: row-major 64x128 bytes, rows = 16 chunks of 8B,
// phys_chunk = chunk ^ (row & 15). 8B-aligned for ds_read/write_b64.
__device__ __forceinline__ int sw8(int row, int chunk) {
    return row * HID + ((chunk ^ (row & 15)) << 3);   // in bytes
}

// Register-only C-operand build (address-taken aggregates spill — R7 lesson)
__device__ __forceinline__ floatx16 ld_bias16(const float* bs, int base) {
    const floatx4 t0 = *(const floatx4*)(&bs[base]);
    const floatx4 t1 = *(const floatx4*)(&bs[base + 8]);
    const floatx4 t2 = *(const floatx4*)(&bs[base + 16]);
    const floatx4 t3 = *(const floatx4*)(&bs[base + 24]);
    floatx16 v = {t0[0], t0[1], t0[2], t0[3], t1[0], t1[1], t1[2], t1[3],
                  t2[0], t2[1], t2[2], t2[3], t3[0], t3[1], t3[2], t3[3]};
    return v;
}

// R12 exact revert — best measured (93.5 us). Double-pumped pipeline: one
// barrier per tile; phase s runs L2(tile s) + L3(tile s-1) as independent
// MFMA chains; parity double-buffered LDS; fp8 weights in regs (32 VGPR) +
// 4 floatx16 accs (64 AGPR) under the proven (256,4) regime.
// Session ledger: LDS-bytes (R9), occupancy (R10/R11 — remat), VALU packing
// (R13/R14) all tested and closed; barrier halving (R12) was the real win.
__launch_bounds__(BLOCK, 4)
__global__ void monotonic_fused(const float* __restrict__ x, const float* __restrict__ h,
                                const float* __restrict__ w1, const float* __restrict__ b1,
                                const float* __restrict__ w2, const float* __restrict__ b2,
                                const float* __restrict__ w3, const float* __restrict__ b3,
                                const float* __restrict__ w4, const float* __restrict__ b4,
                                float* __restrict__ out) {
    __shared__ __align__(16) unsigned char A1[2][MT * HID];  // a1 fp8, 2 x 8 KB
    __shared__ __align__(16) unsigned char A2[2][MT * HID];  // a2 fp8, 2 x 8 KB
    __shared__ float w1s[2 * HID], b1s[HID], b2s[HID], b3s[HID], w4s[HID];
    __shared__ float fs[S51], ts[S51];
    __shared__ float xs[BPB], hs[BPB], osum[BPB];
    __shared__ float posum[2][4][MT];                        // parity x mi x row
    __shared__ unsigned short rowmap[NTILE * MT];            // (bbl<<6)|ss per row

    const int tid = threadIdx.x;
    const int lane = tid & 63;
    const int mi = tid >> 6;      // wave 0..3 = hidden 32-slice
    const int l31 = lane & 31;
    const int hi = lane >> 5;
    const int r1 = tid >> 2;          // L1 writer: row 0..63
    const int cb = (tid & 3) * 4;     // L1 writer: base chunk (4 chunks = 32 k-cols)

    // ---- stage small tensors ----
    w1s[tid] = w1[tid];               // 256 threads = 256 elems exactly
    if (tid < HID) {
        b1s[tid] = b1[tid]; b2s[tid] = b2[tid]; b3s[tid] = b3[tid]; w4s[tid] = w4[tid];
    }
    if (tid < BPB) {
        xs[tid] = x[blockIdx.x * BPB + tid];
        hs[tid] = h[blockIdx.x * BPB + tid];
        osum[tid] = 0.0f;
    }
    for (int i = tid; i < NTILE * MT; i += BLOCK) {
        int lrc = i < RPB ? i : RPB - 1;
        unsigned bbl = (unsigned)lrc / 51u;
        int ss = lrc - (int)bbl * 51;
        rowmap[i] = (unsigned short)((bbl << 6) | ss);
    }
    if (tid < S51) {
        // Faithful port of compute_cc_weights (verified R1-R14)
        const float PI50 = 0.06283185307179586f;  // pi/50
        float acc = 1.0f;
        for (int i = 2; i <= 50; i += 2) {
            int m = (i * tid) % 100;  // exact argument reduction
            acc += (2.0f / (1.0f - (float)(i * i))) * cosf((float)m * PI50);
        }
        float ccw = acc * 0.04f * ((tid == 0 || tid == NSTEP) ? 0.5f : 1.0f);
        fs[tid] = ccw * 0.5f;                               // folds the (x-x0)*0.5 factor
        ts[tid] = (cosf((float)tid * PI50) + 1.0f) * 0.5f;  // (steps+1)/2
    }
    const float b4v = b4[0];

    // ---- gather W2^T / W3^T A-operand fp8 fragments (coalesced over l31) ----
    // frag[kc] byte e = W[kc*16 + hi*8 + e][mi*32 + l31]
    long w2f[8], w3f[8];
    {
        const int irow = mi * 32 + l31;
#pragma unroll
        for (int kc = 0; kc < 8; ++kc) {
            const int kb = kc * 16 + hi * 8;
            unsigned lo2 = pk4_fp8(w2[(kb + 0) * HID + irow], w2[(kb + 1) * HID + irow],
                                   w2[(kb + 2) * HID + irow], w2[(kb + 3) * HID + irow]);
            unsigned hi2 = pk4_fp8(w2[(kb + 4) * HID + irow], w2[(kb + 5) * HID + irow],
                                   w2[(kb + 6) * HID + irow], w2[(kb + 7) * HID + irow]);
            w2f[kc] = (long)(((unsigned long long)hi2 << 32) | lo2);
            unsigned lo3 = pk4_fp8(w3[(kb + 0) * HID + irow], w3[(kb + 1) * HID + irow],
                                   w3[(kb + 2) * HID + irow], w3[(kb + 3) * HID + irow]);
            unsigned hi3 = pk4_fp8(w3[(kb + 4) * HID + irow], w3[(kb + 5) * HID + irow],
                                   w3[(kb + 6) * HID + irow], w3[(kb + 7) * HID + irow]);
            w3f[kc] = (long)(((unsigned long long)hi3 << 32) | lo3);
        }
    }
    __syncthreads();

    // ---- L1 for tile 0 -> A1[0] ----
    {
        unsigned mm = rowmap[r1];
        unsigned bbl = mm >> 6;
        int ss = mm & 63;
        float X = xs[bbl] * ts[ss], hb = hs[bbl];
#pragma unroll
        for (int cc = 0; cc < 4; ++cc) {
            const int kc0 = (cb + cc) * 8;
            float u[8];
#pragma unroll
            for (int e = 0; e < 8; ++e)
                u[e] = fmaxf(fmaf(X, w1s[kc0 + e], fmaf(hb, w1s[HID + kc0 + e], b1s[kc0 + e])), 0.0f);
            unsigned lo = pk4_fp8(u[0], u[1], u[2], u[3]);
            unsigned hi2 = pk4_fp8(u[4], u[5], u[6], u[7]);
            *(unsigned long long*)(&A1[0][sw8(r1, cb + cc)]) =
                ((unsigned long long)hi2 << 32) | lo;
        }
    }
    __syncthreads();

    for (int s = 0; s <= NTILE; ++s) {
        const int pa = s & 1, pb = pa ^ 1;
        floatx16 a0, a1, c0, c1;

        // ---- L2-MFMA on tile s (read A1[pa]); bias as C of peeled MFMA ----
        if (s < NTILE) {
            const floatx16 ci = ld_bias16(b2s, mi * 32 + 4 * hi);
            long f0 = *(const long*)(&A1[pa][sw8(l31, hi)]);
            long f1 = *(const long*)(&A1[pa][sw8(l31 + 32, hi)]);
            a0 = __builtin_amdgcn_mfma_f32_32x32x16_fp8_fp8(w2f[0], f0, ci, 0, 0, 0);
            a1 = __builtin_amdgcn_mfma_f32_32x32x16_fp8_fp8(w2f[0], f1, ci, 0, 0, 0);
#pragma unroll
            for (int kc = 1; kc < 8; ++kc) {
                f0 = *(const long*)(&A1[pa][sw8(l31, kc * 2 + hi)]);
                f1 = *(const long*)(&A1[pa][sw8(l31 + 32, kc * 2 + hi)]);
                a0 = __builtin_amdgcn_mfma_f32_32x32x16_fp8_fp8(w2f[kc], f0, a0, 0, 0, 0);
                a1 = __builtin_amdgcn_mfma_f32_32x32x16_fp8_fp8(w2f[kc], f1, a1, 0, 0, 0);
            }
        }
        // ---- L3-MFMA on tile s-1 (read A2[pb]) — independent chain, overlaps L2 ----
        if (s >= 1) {
            const floatx16 ci = ld_bias16(b3s, mi * 32 + 4 * hi);
            long g0 = *(const long*)(&A2[pb][sw8(l31, hi)]);
            long g1 = *(const long*)(&A2[pb][sw8(l31 + 32, hi)]);
            c0 = __builtin_amdgcn_mfma_f32_32x32x16_fp8_fp8(w3f[0], g0, ci, 0, 0, 0);
            c1 = __builtin_amdgcn_mfma_f32_32x32x16_fp8_fp8(w3f[0], g1, ci, 0, 0, 0);
#pragma unroll
            for (int kc = 1; kc < 8; ++kc) {
                g0 = *(const long*)(&A2[pb][sw8(l31, kc * 2 + hi)]);
                g1 = *(const long*)(&A2[pb][sw8(l31 + 32, kc * 2 + hi)]);
                c0 = __builtin_amdgcn_mfma_f32_32x32x16_fp8_fp8(w3f[kc], g0, c0, 0, 0, 0);
                c1 = __builtin_amdgcn_mfma_f32_32x32x16_fp8_fp8(w3f[kc], g1, c1, 0, 0, 0);
            }
        }
        // ---- consume tile s-2 partials (posum[pa]; written phase s-1, barrier apart) ----
        if (s >= 2 && tid < MT) {
            int lr = (s - 2) * MT + tid;
            float u = posum[pa][0][tid] + posum[pa][1][tid] + posum[pa][2][tid]
                    + posum[pa][3][tid] + b4v;
            if (lr < RPB) {
                unsigned mm = rowmap[lr];
                float dz = u > 0.0f ? u + 1.0f : __expf(u);  // elu(u)+1
                atomicAdd(&osum[mm >> 6], dz * fs[mm & 63]);
            }
        }
        // ---- epilogue: relu(a) -> A2[pa] fp8 ----
        if (s < NTILE) {
#pragma unroll
            for (int g = 0; g < 4; ++g) {
                const int chI = mi * 4 + g;
                unsigned p0 = pk4_fp8(fmaxf(a0[4 * g + 0], 0.0f), fmaxf(a0[4 * g + 1], 0.0f),
                                      fmaxf(a0[4 * g + 2], 0.0f), fmaxf(a0[4 * g + 3], 0.0f));
                *(unsigned*)(&A2[pa][sw8(l31, chI) + 4 * hi]) = p0;
                unsigned p1 = pk4_fp8(fmaxf(a1[4 * g + 0], 0.0f), fmaxf(a1[4 * g + 1], 0.0f),
                                      fmaxf(a1[4 * g + 2], 0.0f), fmaxf(a1[4 * g + 3], 0.0f));
                *(unsigned*)(&A2[pa][sw8(l31 + 32, chI) + 4 * hi]) = p1;
            }
        }
        // ---- fused L4 for tile s-1 -> posum[pb] (plain stores) ----
        if (s >= 1) {
            float p0 = 0.0f, p1 = 0.0f;
#pragma unroll
            for (int g = 0; g < 4; ++g) {
                const floatx4 w4v = *(const floatx4*)(&w4s[mi * 32 + 8 * g + 4 * hi]);
#pragma unroll
                for (int rr = 0; rr < 4; ++rr) {
                    p0 = fmaf(fmaxf(c0[4 * g + rr], 0.0f), w4v[rr], p0);
                    p1 = fmaf(fmaxf(c1[4 * g + rr], 0.0f), w4v[rr], p1);
                }
            }
            p0 += __shfl_xor(p0, 32);
            p1 += __shfl_xor(p1, 32);
            if (hi == 0) {
                posum[pb][mi][l31] = p0;
                posum[pb][mi][l31 + 32] = p1;
            }
        }
        // ---- L1 for tile s+1 -> A1[pb] (A1[pb] last read in phase s-1) ----
        if (s + 1 < NTILE) {
            int lr = (s + 1) * MT + r1;
            unsigned mm = rowmap[lr];
            unsigned bbl = mm >> 6;
            int ss = mm & 63;
            float X = xs[bbl] * ts[ss], hb = hs[bbl];
#pragma unroll
            for (int cc = 0; cc < 4; ++cc) {
                const int kc0 = (cb + cc) * 8;
                float u[8];
#pragma unroll
                for (int e = 0; e < 8; ++e)
                    u[e] = fmaxf(fmaf(X, w1s[kc0 + e], fmaf(hb, w1s[HID + kc0 + e], b1s[kc0 + e])), 0.0f);
                unsigned lo = pk4_fp8(u[0], u[1], u[2], u[3]);
                unsigned hi2 = pk4_fp8(u[4], u[5], u[6], u[7]);
                *(unsigned long long*)(&A1[pb][sw8(r1, cb + cc)]) =
                    ((unsigned long long)hi2 << 32) | lo;
            }
        }
        __syncthreads();
    }

    // final consume: tile NTILE-1 partials (written in phase s=NTILE to posum[(NTILE-1)&1])
    if (tid < MT) {
        int lr = (NTILE - 1) * MT + tid;
        if (lr < RPB) {
            const int pf = (NTILE - 1) & 1;
            float u = posum[pf][0][tid] + posum[pf][1][tid] + posum[pf][2][tid]
                    + posum[pf][3][tid] + b4v;
            unsigned mm = rowmap[lr];
            float dz = u > 0.0f ? u + 1.0f : __expf(u);
            atomicAdd(&osum[mm >> 6], dz * fs[mm & 63]);
        }
    }
    __syncthreads();

    if (tid < BPB) out[blockIdx.x * BPB + tid] = hs[tid] + osum[tid] * xs[tid];
}

extern "C" void kernel_launch(void* const* d_in, const int* in_sizes, int n_in,
                              void* d_out, int out_size, void* d_ws, size_t ws_size,
                              hipStream_t stream) {
    const float* x  = (const float*)d_in[0];
    const float* h  = (const float*)d_in[1];
    const float* w1 = (const float*)d_in[2];
    const float* b1 = (const float*)d_in[3];
    const float* w2 = (const float*)d_in[4];
    const float* b2 = (const float*)d_in[5];
    const float* w3 = (const float*)d_in[6];
    const float* b3 = (const float*)d_in[7];
    const float* w4 = (const float*)d_in[8];
    const float* b4 = (const float*)d_in[9];
    float* out = (float*)d_out;

    monotonic_fused<<<GRID, BLOCK, 0, stream>>>(x, h, w1, b1, w2, b2, w3, b3, w4, b4, out);
}